// Round 4
// baseline (156.074 us; speedup 1.0000x reference)
//
#include <hip/hip_runtime.h>

typedef unsigned short u16;
typedef __attribute__((ext_vector_type(8))) short bf16x8;   // 8 bf16 = 4 VGPRs
typedef __attribute__((ext_vector_type(4))) float f32x4;
typedef __attribute__((ext_vector_type(4))) unsigned int u32x4;
typedef __attribute__((ext_vector_type(2))) unsigned int u32x2;

#define MFMA16(a, b, c) __builtin_amdgcn_mfma_f32_16x16x32_bf16((a), (b), (c), 0, 0, 0)

static constexpr int Bn = 8, Tn = 2048, Cn = 1024, Hn = 128;

static __device__ __forceinline__ u16 f2bf(float f) {
  union { float f; unsigned u; } v;
  v.f = f;
  unsigned r = v.u + 0x7fffu + ((v.u >> 16) & 1u);
  return (u16)(r >> 16);
}

static __device__ __forceinline__ float bf2f(u16 h) {
  union { unsigned u; float f; } v;
  v.u = ((unsigned)h) << 16;
  return v.f;
}

static __device__ __forceinline__ unsigned pack2(float a, float b) {
  return (unsigned)f2bf(a) | ((unsigned)f2bf(b) << 16);
}

// ---------------------------------------------------------------------------
// Kernel 1: transpose + bf16-convert the three weight matrices
// W[C][H] (f32) -> Wt[3][H][C] (bf16).
// ---------------------------------------------------------------------------
__global__ __launch_bounds__(256) void wt_kernel(const float* __restrict__ Wk,
                                                 const float* __restrict__ Wq,
                                                 const float* __restrict__ Wv,
                                                 u16* __restrict__ Wt) {
  __shared__ u16 tile[64][65];
  const int c0 = blockIdx.x * 64;   // 0..960
  const int h0 = blockIdx.y * 64;   // 0,64
  const int z = blockIdx.z;         // 0=k,1=q,2=v
  const float* W = (z == 0) ? Wk : (z == 1) ? Wq : Wv;
  u16* dst = Wt + (size_t)z * Hn * Cn;
  const int tx = threadIdx.x & 63;
  const int ty = threadIdx.x >> 6;  // 0..3
#pragma unroll
  for (int i = 0; i < 16; ++i) {
    int r = ty * 16 + i;
    tile[r][tx] = f2bf(W[(size_t)(c0 + r) * Hn + h0 + tx]);
  }
  __syncthreads();
#pragma unroll
  for (int i = 0; i < 16; ++i) {
    int r = ty * 16 + i;
    dst[(size_t)(h0 + r) * Cn + c0 + tx] = tile[tx][r];
  }
}

// ---------------------------------------------------------------------------
// Kernel 2: fused QKV projection, single pass over X.
// Swapped operands: C^T[h][m] = Wt[h][:k] * X^T[:k][m].
//   A-frag: Wt[habs + l15][k]   (bf16, L2-hot, 768 KB total)
//   B-frag: X[m0 + mf*16 + l15][k] (f32 -> bf16 cvt in regs)
//   C: row = h (lg*4+r), col = m (l15)  -> 4 consecutive h per lane = 8B store.
// Grid: 512 blocks x 256 thr; block owns 32 m-rows; wave w owns h in [96w, 96w+96).
// No LDS, no __syncthreads; register double-buffered K loop.
// ---------------------------------------------------------------------------
__global__ __launch_bounds__(256) void proj_kernel(const float* __restrict__ X,
                                                   const u16* __restrict__ Wt,
                                                   u16* __restrict__ Kb,
                                                   u16* __restrict__ Qb,
                                                   u16* __restrict__ Vt) {
  const int m0 = blockIdx.x * 32;
  const int tid = threadIdx.x;
  const int w = tid >> 6;
  const int lane = tid & 63;
  const int l15 = lane & 15, lg = lane >> 4;
  const int koff = lg * 8;

  const u16* wrow[6];
  const float* xrow[2];
#pragma unroll
  for (int hf = 0; hf < 6; ++hf)
    wrow[hf] = Wt + (size_t)(w * 96 + hf * 16 + l15) * Cn;
#pragma unroll
  for (int mf = 0; mf < 2; ++mf)
    xrow[mf] = X + (size_t)(m0 + mf * 16 + l15) * Cn;

  f32x4 acc[6][2] = {};

  bf16x8 aA[6], aB[6];
  f32x4 pA[2][2], pB[2][2];

#pragma unroll
  for (int hf = 0; hf < 6; ++hf)
    aA[hf] = *reinterpret_cast<const bf16x8*>(wrow[hf] + koff);
#pragma unroll
  for (int mf = 0; mf < 2; ++mf) {
    pA[mf][0] = *reinterpret_cast<const f32x4*>(xrow[mf] + koff);
    pA[mf][1] = *reinterpret_cast<const f32x4*>(xrow[mf] + koff + 4);
  }

  for (int kt = 0; kt < Cn; kt += 64) {
    // prefetch the odd 32-chunk
#pragma unroll
    for (int hf = 0; hf < 6; ++hf)
      aB[hf] = *reinterpret_cast<const bf16x8*>(wrow[hf] + kt + 32 + koff);
#pragma unroll
    for (int mf = 0; mf < 2; ++mf) {
      pB[mf][0] = *reinterpret_cast<const f32x4*>(xrow[mf] + kt + 32 + koff);
      pB[mf][1] = *reinterpret_cast<const f32x4*>(xrow[mf] + kt + 32 + koff + 4);
    }
    // compute on even chunk
    {
      bf16x8 b[2];
#pragma unroll
      for (int mf = 0; mf < 2; ++mf) {
        union { u16 h[8]; bf16x8 v; } cv;
#pragma unroll
        for (int j = 0; j < 4; ++j) {
          cv.h[j] = f2bf(pA[mf][0][j]);
          cv.h[4 + j] = f2bf(pA[mf][1][j]);
        }
        b[mf] = cv.v;
      }
#pragma unroll
      for (int hf = 0; hf < 6; ++hf)
#pragma unroll
        for (int mf = 0; mf < 2; ++mf)
          acc[hf][mf] = MFMA16(aA[hf], b[mf], acc[hf][mf]);
    }
    // prefetch next even chunk
    if (kt + 64 < Cn) {
#pragma unroll
      for (int hf = 0; hf < 6; ++hf)
        aA[hf] = *reinterpret_cast<const bf16x8*>(wrow[hf] + kt + 64 + koff);
#pragma unroll
      for (int mf = 0; mf < 2; ++mf) {
        pA[mf][0] = *reinterpret_cast<const f32x4*>(xrow[mf] + kt + 64 + koff);
        pA[mf][1] = *reinterpret_cast<const f32x4*>(xrow[mf] + kt + 64 + koff + 4);
      }
    }
    // compute on odd chunk
    {
      bf16x8 b[2];
#pragma unroll
      for (int mf = 0; mf < 2; ++mf) {
        union { u16 h[8]; bf16x8 v; } cv;
#pragma unroll
        for (int j = 0; j < 4; ++j) {
          cv.h[j] = f2bf(pB[mf][0][j]);
          cv.h[4 + j] = f2bf(pB[mf][1][j]);
        }
        b[mf] = cv.v;
      }
#pragma unroll
      for (int hf = 0; hf < 6; ++hf)
#pragma unroll
        for (int mf = 0; mf < 2; ++mf)
          acc[hf][mf] = MFMA16(aB[hf], b[mf], acc[hf][mf]);
    }
  }

  // ---- store: lane holds h = habs + lg*4 + r (r=0..3), m = m0 + mf*16 + l15
#pragma unroll
  for (int hf = 0; hf < 6; ++hf) {
    const int habs = w * 96 + hf * 16 + lg * 4;
    const int p = habs >> 7;          // 0=k,1=q,2=v
    const int h = habs & 127;
    const float sc = (p == 1) ? 0.08838834764831845f : 1.0f;
#pragma unroll
    for (int mf = 0; mf < 2; ++mf) {
      const int m = m0 + mf * 16 + l15;
      union { u16 h4[4]; u32x2 v; } pk;
#pragma unroll
      for (int r = 0; r < 4; ++r) pk.h4[r] = f2bf(acc[hf][mf][r] * sc);
      if (p == 0) {
        *reinterpret_cast<u32x2*>(&Kb[(size_t)m * Hn + h]) = pk.v;
      } else if (p == 1) {
        *reinterpret_cast<u32x2*>(&Qb[(size_t)m * Hn + h]) = pk.v;
      } else {
        const int b = m >> 11, t = m & (Tn - 1);
#pragma unroll
        for (int r = 0; r < 4; ++r)
          Vt[((size_t)b * Hn + h + r) * Tn + t] = pk.h4[r];
      }
    }
  }
}

// ---------------------------------------------------------------------------
// Kernel 3: causal flash attention, v3 (swapped QK^T -> lane-local softmax).
// Block = one 16-row q-strip of one batch (heavy-first, batch->XCD pinned);
// 4 waves split 64-key tiles round-robin.
// Per tile: S^T = mfma(K, Q): lane (l15=q, lg) holds S[key=k0+nf*16+lg*4+r][q].
// Softmax per lane: 16 local values + 2 shfl_xor. PV: O^T = mfma(V^T, P^T).
// ---------------------------------------------------------------------------
__global__ __launch_bounds__(256) void attn_kernel(const u16* __restrict__ Qb,
                                                   const u16* __restrict__ Kb,
                                                   const u16* __restrict__ Vt,
                                                   float* __restrict__ Out) {
  __shared__ u16 Om[4][16][132];     // per-wave O^T partials, bf16 (padded)
  __shared__ float Ml[4][16][2];     // per-wave (m, l) per query row
  __shared__ u16 Pl[4][16][72];      // P staging: [q][key] bf16, padded to 144B

  const int batch = blockIdx.x & 7;
  const int srank = blockIdx.x >> 3;       // 0..127, heavy first
  const int q0 = (127 - srank) << 4;
  const int tid = threadIdx.x;
  const int w = tid >> 6;
  const int lane = tid & 63;
  const int l15 = lane & 15, lg = lane >> 4;

  const size_t bt = (size_t)batch * Tn;

  // Q as B-operand: lane reads Q[q0+l15][kk*32 + lg*8 + j]
  bf16x8 qb[4];
#pragma unroll
  for (int kk = 0; kk < 4; ++kk)
    qb[kk] = *reinterpret_cast<const bf16x8*>(&Qb[(bt + q0 + l15) * Hn + kk * 32 + lg * 8]);

  f32x4 o[8] = {};
  float m_r = -1e30f;
  float l_r = 0.f;

  const int nt = (q0 + 16 + 63) >> 6;   // 64-key tiles covering keys 0..q0+15
  for (int t = w; t < nt; t += 4) {
    const int k0 = t << 6;

    // ---- S^T = K Q^T : four 16-key fragments; lane holds q=l15 col
    f32x4 s[4] = {};
#pragma unroll
    for (int nf = 0; nf < 4; ++nf) {
#pragma unroll
      for (int kk = 0; kk < 4; ++kk) {
        bf16x8 ka = *reinterpret_cast<const bf16x8*>(
            &Kb[(bt + k0 + nf * 16 + l15) * Hn + kk * 32 + lg * 8]);
        s[nf] = MFMA16(ka, qb[kk], s[nf]);
      }
    }

    // ---- causal mask (boundary tiles only); key = k0+nf*16+lg*4+r, q = q0+l15
    if (k0 + 63 > q0) {
      const int q = q0 + l15;
#pragma unroll
      for (int nf = 0; nf < 4; ++nf) {
#pragma unroll
        for (int r = 0; r < 4; ++r) {
          if (k0 + nf * 16 + lg * 4 + r > q) s[nf][r] = -1e30f;
        }
      }
    }

    // ---- online softmax: all 64 keys of query q=l15 live in 4 lanes (lg)
    float mx = -1e30f;
#pragma unroll
    for (int nf = 0; nf < 4; ++nf)
#pragma unroll
      for (int r = 0; r < 4; ++r) mx = fmaxf(mx, s[nf][r]);
    mx = fmaxf(mx, __shfl_xor(mx, 16));
    mx = fmaxf(mx, __shfl_xor(mx, 32));
    const float mn = fmaxf(m_r, mx);
    const float sc = __expf(m_r - mn);
    float rs = 0.f;
#pragma unroll
    for (int nf = 0; nf < 4; ++nf)
#pragma unroll
      for (int r = 0; r < 4; ++r) {
        s[nf][r] = __expf(s[nf][r] - mn);
        rs += s[nf][r];
      }
    rs += __shfl_xor(rs, 16);
    rs += __shfl_xor(rs, 32);
    l_r = l_r * sc + rs;
    m_r = mn;
#pragma unroll
    for (int n = 0; n < 8; ++n) o[n] *= sc;

    // ---- P -> LDS (packed b64 per nf), then read as P^T B-fragments
#pragma unroll
    for (int nf = 0; nf < 4; ++nf) {
      u32x2 pv;
      pv.x = pack2(s[nf][0], s[nf][1]);
      pv.y = pack2(s[nf][2], s[nf][3]);
      *reinterpret_cast<u32x2*>(&Pl[w][l15][nf * 16 + lg * 4]) = pv;
    }
    asm volatile("s_waitcnt lgkmcnt(0)" ::: "memory");
    bf16x8 pb0 = *reinterpret_cast<const bf16x8*>(&Pl[w][l15][lg * 8]);
    bf16x8 pb1 = *reinterpret_cast<const bf16x8*>(&Pl[w][l15][32 + lg * 8]);
    asm volatile("" ::: "memory");   // pin reads before next iter's writes

    // ---- O^T += V^T P^T   (A = V^T fragments, contiguous along T)
#pragma unroll
    for (int n = 0; n < 8; ++n) {
      const u16* vp = &Vt[((size_t)batch * Hn + n * 16 + l15) * Tn + k0 + lg * 8];
      bf16x8 va0 = *reinterpret_cast<const bf16x8*>(vp);
      bf16x8 va1 = *reinterpret_cast<const bf16x8*>(vp + 32);
      o[n] = MFMA16(va0, pb0, o[n]);
      o[n] = MFMA16(va1, pb1, o[n]);
    }
  }

  // ---- publish per-wave partials: lane holds O^T[h=n*16+lg*4+r][q=l15]
#pragma unroll
  for (int n = 0; n < 8; ++n) {
    u32x2 ov;
    ov.x = pack2(o[n][0], o[n][1]);
    ov.y = pack2(o[n][2], o[n][3]);
    *reinterpret_cast<u32x2*>(&Om[w][l15][n * 16 + lg * 4]) = ov;
  }
  if (lg == 0) {
    Ml[w][l15][0] = m_r;
    Ml[w][l15][1] = l_r;
  }
  __syncthreads();

  // ---- combine 4 partials; 256 threads cover 16 rows x 128 h (8 h each)
  {
    const int row = tid >> 4;
    const int h0 = (tid & 15) * 8;
    float mw[4], lw[4];
    float M = -1e30f;
#pragma unroll
    for (int i = 0; i < 4; ++i) {
      mw[i] = Ml[i][row][0];
      lw[i] = Ml[i][row][1];
      M = fmaxf(M, mw[i]);
    }
    float e[4], L = 0.f;
#pragma unroll
    for (int i = 0; i < 4; ++i) {
      e[i] = __expf(mw[i] - M);
      L += lw[i] * e[i];
    }
    const float inv = 1.0f / L;
    float outv[8];
#pragma unroll
    for (int j = 0; j < 8; ++j) {
      float a = 0.f;
#pragma unroll
      for (int i = 0; i < 4; ++i) a += e[i] * bf2f(Om[i][row][h0 + j]);
      outv[j] = a * inv;
    }
    float* op = &Out[(bt + q0 + row) * Hn + h0];
    *reinterpret_cast<f32x4*>(op) = *reinterpret_cast<const f32x4*>(&outv[0]);
    *reinterpret_cast<f32x4*>(op + 4) = *reinterpret_cast<const f32x4*>(&outv[4]);
  }
}

// ---------------------------------------------------------------------------
extern "C" void kernel_launch(void* const* d_in, const int* in_sizes, int n_in,
                              void* d_out, int out_size, void* d_ws, size_t ws_size,
                              hipStream_t stream) {
  const float* X = (const float*)d_in[0];
  const float* Wk = (const float*)d_in[1];
  const float* Wq = (const float*)d_in[2];
  const float* Wv = (const float*)d_in[3];

  char* ws = (char*)d_ws;
  u16* Wt = (u16*)(ws);
  u16* Kb = (u16*)(ws + 786432);
  u16* Qb = (u16*)(ws + 786432 + 4194304);
  u16* Vt = (u16*)(ws + 786432 + 2 * 4194304);
  float* Out = (float*)d_out;

  wt_kernel<<<dim3(16, 2, 3), 256, 0, stream>>>(Wk, Wq, Wv, Wt);
  proj_kernel<<<dim3(512), 256, 0, stream>>>(X, Wt, Kb, Qb, Vt);
  attn_kernel<<<dim3(Bn * Tn / 16), 256, 0, stream>>>(Qb, Kb, Vt, Out);
}

// Round 5
// 113.603 us; speedup vs baseline: 1.3739x; 1.3739x over previous
//
#include <hip/hip_runtime.h>

typedef unsigned short u16;
typedef __attribute__((ext_vector_type(8))) short bf16x8;   // 8 bf16 = 4 VGPRs
typedef __attribute__((ext_vector_type(4))) float f32x4;
typedef __attribute__((ext_vector_type(4))) unsigned int u32x4;
typedef __attribute__((ext_vector_type(2))) unsigned int u32x2;

#define MFMA16(a, b, c) __builtin_amdgcn_mfma_f32_16x16x32_bf16((a), (b), (c), 0, 0, 0)

static constexpr int Bn = 8, Tn = 2048, Cn = 1024, Hn = 128;

static __device__ __forceinline__ u16 f2bf(float f) {
  union { float f; unsigned u; } v;
  v.f = f;
  unsigned r = v.u + 0x7fffu + ((v.u >> 16) & 1u);
  return (u16)(r >> 16);
}

static __device__ __forceinline__ float bf2f(u16 h) {
  union { unsigned u; float f; } v;
  v.u = ((unsigned)h) << 16;
  return v.f;
}

static __device__ __forceinline__ unsigned pack2(float a, float b) {
  return (unsigned)f2bf(a) | ((unsigned)f2bf(b) << 16);
}

// ---------------------------------------------------------------------------
// Kernel 1: transpose + bf16-convert W[C][H] (f32) -> Wt[3][H][C] (bf16).
// ---------------------------------------------------------------------------
__global__ __launch_bounds__(256) void wt_kernel(const float* __restrict__ Wk,
                                                 const float* __restrict__ Wq,
                                                 const float* __restrict__ Wv,
                                                 u16* __restrict__ Wt) {
  __shared__ u16 tile[64][65];
  const int c0 = blockIdx.x * 64;   // 0..960
  const int h0 = blockIdx.y * 64;   // 0,64
  const int z = blockIdx.z;         // 0=k,1=q,2=v
  const float* W = (z == 0) ? Wk : (z == 1) ? Wq : Wv;
  u16* dst = Wt + (size_t)z * Hn * Cn;
  const int tx = threadIdx.x & 63;
  const int ty = threadIdx.x >> 6;  // 0..3
#pragma unroll
  for (int i = 0; i < 16; ++i) {
    int r = ty * 16 + i;
    tile[r][tx] = f2bf(W[(size_t)(c0 + r) * Hn + h0 + tx]);
  }
  __syncthreads();
#pragma unroll
  for (int i = 0; i < 16; ++i) {
    int r = ty * 16 + i;
    dst[(size_t)(h0 + r) * Cn + c0 + tx] = tile[tx][r];
  }
}

// ---------------------------------------------------------------------------
// Kernel 2: fused QKV projection, ONE pass over X.
// Block = 64 m-rows x 384 h-cols (all 3 projections); 512 thr = 8 waves;
// wave (wm = w&1, wh = w>>2? no: wh=w>>1) owns 32 m x 96 h.
// Swapped operands: A = W rows (h,k) from Ws, B = X rows (m,k) from Xs.
// C: lane holds h = hf*16+lg*4+r (4 consecutive), m = mf*16+l15.
// K/Q stores packed 8B; V scattered to Vt[B][H][T].
// ---------------------------------------------------------------------------
__global__ __launch_bounds__(512) void proj_kernel(const float* __restrict__ X,
                                                   const u16* __restrict__ Wt,
                                                   u16* __restrict__ Kb,
                                                   u16* __restrict__ Qb,
                                                   u16* __restrict__ Vt) {
  __shared__ u16 Xs[64][72];    // 9.2 KB, bf16, rows=m, cols=k
  __shared__ u16 Ws[384][72];   // 55.3 KB, rows=h(3 proj), cols=k

  const int m0 = blockIdx.x * 64;
  const int tid = threadIdx.x;
  const int w = tid >> 6;            // 0..7
  const int wm = w & 1;              // m-half
  const int wh = w >> 1;             // h-quarter (96 h each)
  const int lane = tid & 63;
  const int l15 = lane & 15, lg = lane >> 4;

  // staging assignments
  const int trow = tid >> 3;         // 0..63   (X rows)
  const int tcol = (tid & 7) * 8;    // 0..56   (8 f32 per thread)

  f32x4 acc[6][2] = {};

  for (int kt = 0; kt < Cn; kt += 64) {
    // ---- load to regs (overlaps previous tile's MFMA in other waves)
    f32x4 x0 = *reinterpret_cast<const f32x4*>(&X[(size_t)(m0 + trow) * Cn + kt + tcol]);
    f32x4 x1 = *reinterpret_cast<const f32x4*>(&X[(size_t)(m0 + trow) * Cn + kt + tcol + 4]);
    bf16x8 wreg[6];
    int wrow[6], wc8[6];
#pragma unroll
    for (int i = 0; i < 6; ++i) {
      const int idx = tid + i * 512;        // 0..3071
      wrow[i] = idx >> 3;                   // 0..383
      wc8[i] = (idx & 7) * 8;               // 0..56
      wreg[i] = *reinterpret_cast<const bf16x8*>(&Wt[(size_t)wrow[i] * Cn + kt + wc8[i]]);
    }
    __syncthreads();   // previous tile fully consumed
    // ---- write LDS
    union { u16 h[8]; bf16x8 v; } cv;
#pragma unroll
    for (int j = 0; j < 4; ++j) {
      cv.h[j] = f2bf(x0[j]);
      cv.h[4 + j] = f2bf(x1[j]);
    }
    *reinterpret_cast<bf16x8*>(&Xs[trow][tcol]) = cv.v;
#pragma unroll
    for (int i = 0; i < 6; ++i)
      *reinterpret_cast<bf16x8*>(&Ws[wrow[i]][wc8[i]]) = wreg[i];
    __syncthreads();
    // ---- compute
#pragma unroll
    for (int kk = 0; kk < 2; ++kk) {
      const int ko = kk * 32 + lg * 8;
      bf16x8 wa[6], xb[2];
#pragma unroll
      for (int hf = 0; hf < 6; ++hf)
        wa[hf] = *reinterpret_cast<const bf16x8*>(&Ws[wh * 96 + hf * 16 + l15][ko]);
#pragma unroll
      for (int mf = 0; mf < 2; ++mf)
        xb[mf] = *reinterpret_cast<const bf16x8*>(&Xs[wm * 32 + mf * 16 + l15][ko]);
#pragma unroll
      for (int hf = 0; hf < 6; ++hf)
#pragma unroll
        for (int mf = 0; mf < 2; ++mf)
          acc[hf][mf] = MFMA16(wa[hf], xb[mf], acc[hf][mf]);
    }
  }

  // ---- store
#pragma unroll
  for (int hf = 0; hf < 6; ++hf) {
    const int habs = wh * 96 + hf * 16 + lg * 4;  // 0..383
    const int p = habs >> 7;                      // 0=k,1=q,2=v
    const int h = habs & 127;
    const float sc = (p == 1) ? 0.08838834764831845f : 1.0f;
#pragma unroll
    for (int mf = 0; mf < 2; ++mf) {
      const int m = m0 + wm * 32 + mf * 16 + l15;
      union { u16 h4[4]; u32x2 v; } pk;
#pragma unroll
      for (int r = 0; r < 4; ++r) pk.h4[r] = f2bf(acc[hf][mf][r] * sc);
      if (p == 0) {
        *reinterpret_cast<u32x2*>(&Kb[(size_t)m * Hn + h]) = pk.v;
      } else if (p == 1) {
        *reinterpret_cast<u32x2*>(&Qb[(size_t)m * Hn + h]) = pk.v;
      } else {
        const int b = m >> 11, t = m & (Tn - 1);
#pragma unroll
        for (int r = 0; r < 4; ++r)
          Vt[((size_t)b * Hn + h + r) * Tn + t] = pk.h4[r];
      }
    }
  }
}

// ---------------------------------------------------------------------------
// Kernel 3: causal flash attention (swapped QK^T, lane-local softmax),
// KVBLK = 128 keys per wave-iteration.
// Block = one 16-row q-strip (heavy-first, batch->XCD pinned); 4 waves split
// 128-key tiles round-robin; bf16 partial combine at the end.
// ---------------------------------------------------------------------------
__global__ __launch_bounds__(256) void attn_kernel(const u16* __restrict__ Qb,
                                                   const u16* __restrict__ Kb,
                                                   const u16* __restrict__ Vt,
                                                   float* __restrict__ Out) {
  __shared__ u16 Om[4][16][136];     // per-wave O^T partials, bf16 (17.4 KB)
  __shared__ float Ml[4][16][2];     // per-wave (m, l) per query row
  __shared__ u16 Pl[4][16][140];     // P staging [q][key], padded (17.9 KB)

  const int batch = blockIdx.x & 7;
  const int srank = blockIdx.x >> 3;       // 0..127, heavy first
  const int q0 = (127 - srank) << 4;
  const int tid = threadIdx.x;
  const int w = tid >> 6;
  const int lane = tid & 63;
  const int l15 = lane & 15, lg = lane >> 4;

  const size_t bt = (size_t)batch * Tn;

  // Q as B-operand: lane reads Q[q0+l15][kk*32 + lg*8 + j]
  bf16x8 qb[4];
#pragma unroll
  for (int kk = 0; kk < 4; ++kk)
    qb[kk] = *reinterpret_cast<const bf16x8*>(&Qb[(bt + q0 + l15) * Hn + kk * 32 + lg * 8]);

  f32x4 o[8] = {};
  float m_r = -1e30f;
  float l_r = 0.f;

  const int nt = (q0 + 16 + 127) >> 7;   // 128-key tiles covering keys 0..q0+15
  for (int t = w; t < nt; t += 4) {
    const int k0 = t << 7;

    // ---- S^T = K Q^T : eight 16-key fragments; lane holds q=l15 col
    f32x4 s[8] = {};
#pragma unroll
    for (int nf = 0; nf < 8; ++nf) {
#pragma unroll
      for (int kk = 0; kk < 4; ++kk) {
        bf16x8 ka = *reinterpret_cast<const bf16x8*>(
            &Kb[(bt + k0 + nf * 16 + l15) * Hn + kk * 32 + lg * 8]);
        s[nf] = MFMA16(ka, qb[kk], s[nf]);
      }
    }

    // ---- causal mask (boundary tiles only); key = k0+nf*16+lg*4+r, q = q0+l15
    if (k0 + 127 > q0) {
      const int q = q0 + l15;
#pragma unroll
      for (int nf = 0; nf < 8; ++nf) {
#pragma unroll
        for (int r = 0; r < 4; ++r) {
          if (k0 + nf * 16 + lg * 4 + r > q) s[nf][r] = -1e30f;
        }
      }
    }

    // ---- online softmax: all 128 keys of query q=l15 live in lanes {l15+16*lg}
    float mx = -1e30f;
#pragma unroll
    for (int nf = 0; nf < 8; ++nf)
#pragma unroll
      for (int r = 0; r < 4; ++r) mx = fmaxf(mx, s[nf][r]);
    mx = fmaxf(mx, __shfl_xor(mx, 16));
    mx = fmaxf(mx, __shfl_xor(mx, 32));
    const float mn = fmaxf(m_r, mx);
    const float sc = __expf(m_r - mn);
    float rs = 0.f;
#pragma unroll
    for (int nf = 0; nf < 8; ++nf)
#pragma unroll
      for (int r = 0; r < 4; ++r) {
        s[nf][r] = __expf(s[nf][r] - mn);
        rs += s[nf][r];
      }
    rs += __shfl_xor(rs, 16);
    rs += __shfl_xor(rs, 32);
    l_r = l_r * sc + rs;
    m_r = mn;
#pragma unroll
    for (int n = 0; n < 8; ++n) o[n] *= sc;

    // ---- P -> LDS (packed b64 per nf), then read as P^T B-fragments
#pragma unroll
    for (int nf = 0; nf < 8; ++nf) {
      u32x2 pv;
      pv.x = pack2(s[nf][0], s[nf][1]);
      pv.y = pack2(s[nf][2], s[nf][3]);
      *reinterpret_cast<u32x2*>(&Pl[w][l15][nf * 16 + lg * 4]) = pv;
    }
    asm volatile("s_waitcnt lgkmcnt(0)" ::: "memory");
    bf16x8 pb[4];
#pragma unroll
    for (int ks = 0; ks < 4; ++ks)
      pb[ks] = *reinterpret_cast<const bf16x8*>(&Pl[w][l15][ks * 32 + lg * 8]);
    asm volatile("" ::: "memory");   // pin reads before next iter's writes

    // ---- O^T += V^T P^T   (A = V^T fragments, contiguous along T)
#pragma unroll
    for (int n = 0; n < 8; ++n) {
      const u16* vp = &Vt[((size_t)batch * Hn + n * 16 + l15) * Tn + k0 + lg * 8];
#pragma unroll
      for (int ks = 0; ks < 4; ++ks) {
        bf16x8 va = *reinterpret_cast<const bf16x8*>(vp + ks * 32);
        o[n] = MFMA16(va, pb[ks], o[n]);
      }
    }
  }

  // ---- publish per-wave partials: lane holds O^T[h=n*16+lg*4+r][q=l15]
#pragma unroll
  for (int n = 0; n < 8; ++n) {
    u32x2 ov;
    ov.x = pack2(o[n][0], o[n][1]);
    ov.y = pack2(o[n][2], o[n][3]);
    *reinterpret_cast<u32x2*>(&Om[w][l15][n * 16 + lg * 4]) = ov;
  }
  if (lg == 0) {
    Ml[w][l15][0] = m_r;
    Ml[w][l15][1] = l_r;
  }
  __syncthreads();

  // ---- combine 4 partials; 256 threads cover 16 rows x 128 h (8 h each)
  {
    const int row = tid >> 4;
    const int h0 = (tid & 15) * 8;
    float mw[4], lw[4];
    float M = -1e30f;
#pragma unroll
    for (int i = 0; i < 4; ++i) {
      mw[i] = Ml[i][row][0];
      lw[i] = Ml[i][row][1];
      M = fmaxf(M, mw[i]);
    }
    float e[4], L = 0.f;
#pragma unroll
    for (int i = 0; i < 4; ++i) {
      e[i] = __expf(mw[i] - M);
      L += lw[i] * e[i];
    }
    const float inv = 1.0f / L;
    float outv[8] = {};
#pragma unroll
    for (int i = 0; i < 4; ++i) {
      u32x4 ov = *reinterpret_cast<const u32x4*>(&Om[i][row][h0]);
#pragma unroll
      for (int j = 0; j < 4; ++j) {
        outv[2 * j] += e[i] * bf2f((u16)(ov[j] & 0xffffu));
        outv[2 * j + 1] += e[i] * bf2f((u16)(ov[j] >> 16));
      }
    }
#pragma unroll
    for (int j = 0; j < 8; ++j) outv[j] *= inv;
    float* op = &Out[(bt + q0 + row) * Hn + h0];
    *reinterpret_cast<f32x4*>(op) = *reinterpret_cast<const f32x4*>(&outv[0]);
    *reinterpret_cast<f32x4*>(op + 4) = *reinterpret_cast<const f32x4*>(&outv[4]);
  }
}

// ---------------------------------------------------------------------------
extern "C" void kernel_launch(void* const* d_in, const int* in_sizes, int n_in,
                              void* d_out, int out_size, void* d_ws, size_t ws_size,
                              hipStream_t stream) {
  const float* X = (const float*)d_in[0];
  const float* Wk = (const float*)d_in[1];
  const float* Wq = (const float*)d_in[2];
  const float* Wv = (const float*)d_in[3];

  char* ws = (char*)d_ws;
  u16* Wt = (u16*)(ws);
  u16* Kb = (u16*)(ws + 786432);
  u16* Qb = (u16*)(ws + 786432 + 4194304);
  u16* Vt = (u16*)(ws + 786432 + 2 * 4194304);
  float* Out = (float*)d_out;

  wt_kernel<<<dim3(16, 2, 3), 256, 0, stream>>>(Wk, Wq, Wv, Wt);
  proj_kernel<<<dim3(256), 512, 0, stream>>>(X, Wt, Kb, Qb, Vt);
  attn_kernel<<<dim3(Bn * Tn / 16), 256, 0, stream>>>(Qb, Kb, Vt, Out);
}

// Round 6
// 77.199 us; speedup vs baseline: 2.0217x; 1.4716x over previous
//
#include <hip/hip_runtime.h>

typedef unsigned short u16;
typedef __attribute__((ext_vector_type(8))) short bf16x8;   // 8 bf16 = 4 VGPRs
typedef __attribute__((ext_vector_type(4))) float f32x4;
typedef __attribute__((ext_vector_type(4))) unsigned int u32x4;
typedef __attribute__((ext_vector_type(2))) unsigned int u32x2;

#define MFMA16(a, b, c) __builtin_amdgcn_mfma_f32_16x16x32_bf16((a), (b), (c), 0, 0, 0)

static constexpr int Bn = 8, Tn = 2048, Cn = 1024, Hn = 128;

static __device__ __forceinline__ u16 f2bf(float f) {
  union { float f; unsigned u; } v;
  v.f = f;
  unsigned r = v.u + 0x7fffu + ((v.u >> 16) & 1u);
  return (u16)(r >> 16);
}

static __device__ __forceinline__ float bf2f(u16 h) {
  union { unsigned u; float f; } v;
  v.u = ((unsigned)h) << 16;
  return v.f;
}

static __device__ __forceinline__ unsigned pack2(float a, float b) {
  return (unsigned)f2bf(a) | ((unsigned)f2bf(b) << 16);
}

// ---------------------------------------------------------------------------
// Kernel 1: transpose + bf16-convert W[C][H] (f32) -> Wt[3][H][C] (bf16).
// ---------------------------------------------------------------------------
__global__ __launch_bounds__(256) void wt_kernel(const float* __restrict__ Wk,
                                                 const float* __restrict__ Wq,
                                                 const float* __restrict__ Wv,
                                                 u16* __restrict__ Wt) {
  __shared__ u16 tile[64][65];
  const int c0 = blockIdx.x * 64;   // 0..960
  const int h0 = blockIdx.y * 64;   // 0,64
  const int z = blockIdx.z;         // 0=k,1=q,2=v
  const float* W = (z == 0) ? Wk : (z == 1) ? Wq : Wv;
  u16* dst = Wt + (size_t)z * Hn * Cn;
  const int tx = threadIdx.x & 63;
  const int ty = threadIdx.x >> 6;  // 0..3
#pragma unroll
  for (int i = 0; i < 16; ++i) {
    int r = ty * 16 + i;
    tile[r][tx] = f2bf(W[(size_t)(c0 + r) * Hn + h0 + tx]);
  }
  __syncthreads();
#pragma unroll
  for (int i = 0; i < 16; ++i) {
    int r = ty * 16 + i;
    dst[(size_t)(h0 + r) * Cn + c0 + tx] = tile[tx][r];
  }
}

// ---------------------------------------------------------------------------
// Kernel 2: fused QKV projection, ONE pass over X.
// Block = 64 m-rows x 384 h-cols; 512 thr = 8 waves; wave (wm=w&1, wh=w>>1)
// owns 32 m x 96 h.  Swapped operands: A = W rows, B = X rows.
// K/Q: packed 8B stores.  V: LDS transpose -> packed 32B row-chunks of Vt.
// ---------------------------------------------------------------------------
__global__ __launch_bounds__(512) void proj_kernel(const float* __restrict__ X,
                                                   const u16* __restrict__ Wt,
                                                   u16* __restrict__ Kb,
                                                   u16* __restrict__ Qb,
                                                   u16* __restrict__ Vt) {
  __shared__ u16 Xs[64][72];     // 9.2 KB
  __shared__ u16 Ws[384][72];    // 55.3 KB
  __shared__ u16 Vtmp[128][72];  // 18.4 KB, V^T staging: [h][m_local]

  const int m0 = blockIdx.x * 64;
  const int tid = threadIdx.x;
  const int w = tid >> 6;            // 0..7
  const int wm = w & 1;              // m-half
  const int wh = w >> 1;             // h-quarter (96 h each)
  const int lane = tid & 63;
  const int l15 = lane & 15, lg = lane >> 4;

  const int trow = tid >> 3;         // 0..63   (X rows)
  const int tcol = (tid & 7) * 8;    // 0..56

  f32x4 acc[6][2] = {};

  for (int kt = 0; kt < Cn; kt += 64) {
    f32x4 x0 = *reinterpret_cast<const f32x4*>(&X[(size_t)(m0 + trow) * Cn + kt + tcol]);
    f32x4 x1 = *reinterpret_cast<const f32x4*>(&X[(size_t)(m0 + trow) * Cn + kt + tcol + 4]);
    bf16x8 wreg[6];
    int wrow[6], wc8[6];
#pragma unroll
    for (int i = 0; i < 6; ++i) {
      const int idx = tid + i * 512;        // 0..3071
      wrow[i] = idx >> 3;                   // 0..383
      wc8[i] = (idx & 7) * 8;               // 0..56
      wreg[i] = *reinterpret_cast<const bf16x8*>(&Wt[(size_t)wrow[i] * Cn + kt + wc8[i]]);
    }
    __syncthreads();   // previous tile fully consumed
    union { u16 h[8]; bf16x8 v; } cv;
#pragma unroll
    for (int j = 0; j < 4; ++j) {
      cv.h[j] = f2bf(x0[j]);
      cv.h[4 + j] = f2bf(x1[j]);
    }
    *reinterpret_cast<bf16x8*>(&Xs[trow][tcol]) = cv.v;
#pragma unroll
    for (int i = 0; i < 6; ++i)
      *reinterpret_cast<bf16x8*>(&Ws[wrow[i]][wc8[i]]) = wreg[i];
    __syncthreads();
#pragma unroll
    for (int kk = 0; kk < 2; ++kk) {
      const int ko = kk * 32 + lg * 8;
      bf16x8 wa[6], xb[2];
#pragma unroll
      for (int hf = 0; hf < 6; ++hf)
        wa[hf] = *reinterpret_cast<const bf16x8*>(&Ws[wh * 96 + hf * 16 + l15][ko]);
#pragma unroll
      for (int mf = 0; mf < 2; ++mf)
        xb[mf] = *reinterpret_cast<const bf16x8*>(&Xs[wm * 32 + mf * 16 + l15][ko]);
#pragma unroll
      for (int hf = 0; hf < 6; ++hf)
#pragma unroll
        for (int mf = 0; mf < 2; ++mf)
          acc[hf][mf] = MFMA16(wa[hf], xb[mf], acc[hf][mf]);
    }
  }

  // ---- store K/Q direct; V via LDS transpose
#pragma unroll
  for (int hf = 0; hf < 6; ++hf) {
    const int habs = wh * 96 + hf * 16 + lg * 4;  // 0..380
    const int p = habs >> 7;                      // 0=k,1=q,2=v
    const int h = habs & 127;
    const float sc = (p == 1) ? 0.08838834764831845f : 1.0f;
#pragma unroll
    for (int mf = 0; mf < 2; ++mf) {
      const int m = m0 + wm * 32 + mf * 16 + l15;
      const int ml = wm * 32 + mf * 16 + l15;
      if (p == 0) {
        union { u16 h4[4]; u32x2 v; } pk;
#pragma unroll
        for (int r = 0; r < 4; ++r) pk.h4[r] = f2bf(acc[hf][mf][r]);
        *reinterpret_cast<u32x2*>(&Kb[(size_t)m * Hn + h]) = pk.v;
      } else if (p == 1) {
        union { u16 h4[4]; u32x2 v; } pk;
#pragma unroll
        for (int r = 0; r < 4; ++r) pk.h4[r] = f2bf(acc[hf][mf][r] * sc);
        *reinterpret_cast<u32x2*>(&Qb[(size_t)m * Hn + h]) = pk.v;
      } else {
#pragma unroll
        for (int r = 0; r < 4; ++r) Vtmp[h + r][ml] = f2bf(acc[hf][mf][r]);
      }
    }
  }
  __syncthreads();
  // readback: thread -> (h = tid>>2, c = tid&3): 16 m-values = 32 B
  {
    const int h = tid >> 2;
    const int c = (tid & 3) * 16;
    const int bV = m0 >> 11;
    const int t0 = m0 & (Tn - 1);
    u32x4 v0 = *reinterpret_cast<const u32x4*>(&Vtmp[h][c]);
    u32x4 v1 = *reinterpret_cast<const u32x4*>(&Vtmp[h][c + 8]);
    u16* dst = &Vt[((size_t)bV * Hn + h) * Tn + t0 + c];
    *reinterpret_cast<u32x4*>(dst) = v0;
    *reinterpret_cast<u32x4*>(dst + 8) = v1;
  }
}

// ---------------------------------------------------------------------------
// Kernel 3: causal flash attention v4 — K/V LDS-shared across 8 waves.
// Block = 64 q-rows of one batch (256 blocks, batch->XCD pinned, heavy-first).
// Per 128-key tile: stage K-tile + V^T-tile in LDS (reg-prefetched), then
// wave (strip=w>>1, parity=w&1) computes its 16q x 64key quadrant with
// swapped QK^T + lane-local softmax.  2-partial combine per strip at the end.
// ---------------------------------------------------------------------------
__global__ __launch_bounds__(512) void attn_kernel(const u16* __restrict__ Qb,
                                                   const u16* __restrict__ Kb,
                                                   const u16* __restrict__ Vt,
                                                   float* __restrict__ Out) {
  __shared__ u16 Ks[128][136];       // 34.8 KB  [key][h]
  __shared__ u16 Vs[128][136];       // 34.8 KB  [h][key]
  __shared__ u16 Pl[8][16][72];      // 18.4 KB  per-wave P staging [q][key]
  __shared__ u16 Om[8][16][136];     // 34.8 KB  per-wave O^T partials [q][h]
  __shared__ float Ml[8][16][2];     // 1 KB

  const int batch = blockIdx.x & 7;
  const int rrank = blockIdx.x >> 3;       // 0..31, heavy first
  const int q0 = (31 - rrank) << 6;        // 64-row quad base
  const int tid = threadIdx.x;
  const int w = tid >> 6;                  // 0..7
  const int sw = w >> 1;                   // strip 0..3
  const int par = w & 1;                   // key-half parity
  const int lane = tid & 63;
  const int l15 = lane & 15, lg = lane >> 4;

  const size_t bt = (size_t)batch * Tn;
  const int qrow = q0 + sw * 16;           // strip base
  const int q = qrow + l15;

  // Q B-fragments for this wave's strip
  bf16x8 qb[4];
#pragma unroll
  for (int kk = 0; kk < 4; ++kk)
    qb[kk] = *reinterpret_cast<const bf16x8*>(&Qb[(bt + q) * Hn + kk * 32 + lg * 8]);

  f32x4 o[8] = {};
  float m_r = -1e30f;
  float l_r = 0.f;

  const int nt = (q0 + 64 + 127) >> 7;     // 128-key tiles

  // staging: thread covers 4 K-chunks + 4 V-chunks (16B each)
  u32x4 kreg[4], vreg[4];
#pragma unroll
  for (int i = 0; i < 4; ++i) {
    const int idx = tid + i * 512;
    const int row = idx >> 4, c8 = (idx & 15) * 8;
    kreg[i] = *reinterpret_cast<const u32x4*>(&Kb[(bt + row) * Hn + c8]);
    vreg[i] = *reinterpret_cast<const u32x4*>(&Vt[((size_t)batch * Hn + row) * Tn + c8]);
  }

  for (int t = 0; t < nt; ++t) {
    __syncthreads();   // previous tile consumed
#pragma unroll
    for (int i = 0; i < 4; ++i) {
      const int idx = tid + i * 512;
      const int row = idx >> 4, c8 = (idx & 15) * 8;
      *reinterpret_cast<u32x4*>(&Ks[row][c8]) = kreg[i];
      *reinterpret_cast<u32x4*>(&Vs[row][c8]) = vreg[i];
    }
    __syncthreads();   // tile ready
    const int k0 = t << 7;
    if (t + 1 < nt) {
      const int kn = (t + 1) << 7;
#pragma unroll
      for (int i = 0; i < 4; ++i) {
        const int idx = tid + i * 512;
        const int row = idx >> 4, c8 = (idx & 15) * 8;
        kreg[i] = *reinterpret_cast<const u32x4*>(&Kb[(bt + kn + row) * Hn + c8]);
        vreg[i] = *reinterpret_cast<const u32x4*>(&Vt[((size_t)batch * Hn + row) * Tn + kn + c8]);
      }
    }

    const int kbase = k0 + par * 64;
    if (kbase <= qrow) {   // else: every key masked for this wave -> skip
      // ---- S^T = K Q^T : four 16-key fragments, q = l15 column
      f32x4 s[4] = {};
#pragma unroll
      for (int nf = 0; nf < 4; ++nf) {
#pragma unroll
        for (int kk = 0; kk < 4; ++kk) {
          bf16x8 ka = *reinterpret_cast<const bf16x8*>(
              &Ks[par * 64 + nf * 16 + l15][kk * 32 + lg * 8]);
          s[nf] = MFMA16(ka, qb[kk], s[nf]);
        }
      }

      // ---- causal mask (boundary only): key = kbase+nf*16+lg*4+r vs q
      if (kbase + 63 > qrow) {
#pragma unroll
        for (int nf = 0; nf < 4; ++nf)
#pragma unroll
          for (int r = 0; r < 4; ++r)
            if (kbase + nf * 16 + lg * 4 + r > q) s[nf][r] = -1e30f;
      }

      // ---- online softmax (64 keys live in 4 lg-lanes per query)
      float mx = -1e30f;
#pragma unroll
      for (int nf = 0; nf < 4; ++nf)
#pragma unroll
        for (int r = 0; r < 4; ++r) mx = fmaxf(mx, s[nf][r]);
      mx = fmaxf(mx, __shfl_xor(mx, 16));
      mx = fmaxf(mx, __shfl_xor(mx, 32));
      const float mn = fmaxf(m_r, mx);
      const float sc = __expf(m_r - mn);
      float rs = 0.f;
#pragma unroll
      for (int nf = 0; nf < 4; ++nf)
#pragma unroll
        for (int r = 0; r < 4; ++r) {
          s[nf][r] = __expf(s[nf][r] - mn);
          rs += s[nf][r];
        }
      rs += __shfl_xor(rs, 16);
      rs += __shfl_xor(rs, 32);
      l_r = l_r * sc + rs;
      m_r = mn;
#pragma unroll
      for (int n = 0; n < 8; ++n) o[n] *= sc;

      // ---- P -> Pl (wave-private; barrier-paced loop makes WAR safe)
#pragma unroll
      for (int nf = 0; nf < 4; ++nf) {
        u32x2 pv;
        pv.x = pack2(s[nf][0], s[nf][1]);
        pv.y = pack2(s[nf][2], s[nf][3]);
        *reinterpret_cast<u32x2*>(&Pl[w][l15][nf * 16 + lg * 4]) = pv;
      }
      asm volatile("s_waitcnt lgkmcnt(0)" ::: "memory");
      __builtin_amdgcn_sched_barrier(0);
      bf16x8 pb[2];
#pragma unroll
      for (int ks = 0; ks < 2; ++ks)
        pb[ks] = *reinterpret_cast<const bf16x8*>(&Pl[w][l15][ks * 32 + lg * 8]);

      // ---- O^T += V^T P^T
#pragma unroll
      for (int n = 0; n < 8; ++n) {
#pragma unroll
        for (int ks = 0; ks < 2; ++ks) {
          bf16x8 va = *reinterpret_cast<const bf16x8*>(
              &Vs[n * 16 + l15][par * 64 + ks * 32 + lg * 8]);
          o[n] = MFMA16(va, pb[ks], o[n]);
        }
      }
    }
  }

  // ---- publish per-wave partials: lane holds O^T[h=n*16+lg*4+r][q=l15]
#pragma unroll
  for (int n = 0; n < 8; ++n) {
    u32x2 ov;
    ov.x = pack2(o[n][0], o[n][1]);
    ov.y = pack2(o[n][2], o[n][3]);
    *reinterpret_cast<u32x2*>(&Om[w][l15][n * 16 + lg * 4]) = ov;
  }
  if (lg == 0) {
    Ml[w][l15][0] = m_r;
    Ml[w][l15][1] = l_r;
  }
  __syncthreads();

  // ---- combine the 2 parity partials per strip; write f32 output
  {
    const int row = tid >> 3;          // 0..63
    const int h0 = (tid & 7) * 16;     // 0..112
    const int s_ = row >> 4;
    const int r16 = row & 15;
    const int w0 = s_ * 2, w1 = w0 + 1;
    const float m0v = Ml[w0][r16][0], l0v = Ml[w0][r16][1];
    const float m1v = Ml[w1][r16][0], l1v = Ml[w1][r16][1];
    const float M = fmaxf(m0v, m1v);
    const float e0 = __expf(m0v - M), e1 = __expf(m1v - M);
    const float inv = 1.0f / (l0v * e0 + l1v * e1);
    u32x4 a0 = *reinterpret_cast<const u32x4*>(&Om[w0][r16][h0]);
    u32x4 a1 = *reinterpret_cast<const u32x4*>(&Om[w0][r16][h0 + 8]);
    u32x4 b0 = *reinterpret_cast<const u32x4*>(&Om[w1][r16][h0]);
    u32x4 b1 = *reinterpret_cast<const u32x4*>(&Om[w1][r16][h0 + 8]);
    float outv[16];
#pragma unroll
    for (int j = 0; j < 4; ++j) {
      outv[2 * j]     = (e0 * bf2f((u16)(a0[j] & 0xffffu)) + e1 * bf2f((u16)(b0[j] & 0xffffu))) * inv;
      outv[2 * j + 1] = (e0 * bf2f((u16)(a0[j] >> 16))     + e1 * bf2f((u16)(b0[j] >> 16))) * inv;
      outv[8 + 2 * j]     = (e0 * bf2f((u16)(a1[j] & 0xffffu)) + e1 * bf2f((u16)(b1[j] & 0xffffu))) * inv;
      outv[8 + 2 * j + 1] = (e0 * bf2f((u16)(a1[j] >> 16))     + e1 * bf2f((u16)(b1[j] >> 16))) * inv;
    }
    float* op = &Out[(bt + q0 + row) * Hn + h0];
#pragma unroll
    for (int j = 0; j < 4; ++j)
      *reinterpret_cast<f32x4*>(op + j * 4) = *reinterpret_cast<const f32x4*>(&outv[j * 4]);
  }
}

// ---------------------------------------------------------------------------
extern "C" void kernel_launch(void* const* d_in, const int* in_sizes, int n_in,
                              void* d_out, int out_size, void* d_ws, size_t ws_size,
                              hipStream_t stream) {
  const float* X = (const float*)d_in[0];
  const float* Wk = (const float*)d_in[1];
  const float* Wq = (const float*)d_in[2];
  const float* Wv = (const float*)d_in[3];

  char* ws = (char*)d_ws;
  u16* Wt = (u16*)(ws);
  u16* Kb = (u16*)(ws + 786432);
  u16* Qb = (u16*)(ws + 786432 + 4194304);
  u16* Vt = (u16*)(ws + 786432 + 2 * 4194304);
  float* Out = (float*)d_out;

  wt_kernel<<<dim3(16, 2, 3), 256, 0, stream>>>(Wk, Wq, Wv, Wt);
  proj_kernel<<<dim3(256), 512, 0, stream>>>(X, Wt, Kb, Qb, Vt);
  attn_kernel<<<dim3(Bn * 32), 512, 0, stream>>>(Qb, Kb, Vt, Out);
}